// Round 2
// baseline (1248.925 us; speedup 1.0000x reference)
//
#include <hip/hip_runtime.h>
#include <math.h>

#define F_ 48
#define G_ 4
#define C_ 128
#define HW 16384
#define SCALE_C 0.999f
#define TPB 256

// ws float offsets
#define WS_WT    0            // [128][192]  (kept for layout stability, unused by main)
#define WS_W2    24576        // [192][128]  W2[f*4+g][c] = Wf[g][f][c]
#define WS_QE    49152        // [48][4][4]  (l,g)  Q/sigma^2
#define WS_QN    49920        // [48][4][4]  (g,l)  Q
#define WS_QS    50688        // [48]        SCALE/taus
#define WS_SCAL  50736        // [2][48]
#define WS_ISCAL 50832        // [2][48]
#define WS_MISC  50928        // lamb_e, eps_e, inv_denom

typedef float v2f __attribute__((ext_vector_type(2)));

__global__ void setup_kernel(const float* __restrict__ sigma,
                             const float* __restrict__ Qp,
                             const float* __restrict__ taus_p,
                             const float* __restrict__ lamb,
                             const float* __restrict__ eps_om,
                             const float* __restrict__ mw1, const float* __restrict__ mb1,
                             const float* __restrict__ mw2, const float* __restrict__ mb2,
                             const float* __restrict__ mw3, const float* __restrict__ mb3,
                             const float* __restrict__ Wf,
                             float* __restrict__ ws)
{
    const int tid = threadIdx.x;
    // Reordered copies of Wf (row = f*4+g, f-major)
    for (int i = tid; i < G_ * F_ * C_; i += TPB) {
        int g = i / (F_ * C_);
        int f = (i / C_) % F_;
        int c = i % C_;
        float v = Wf[i];
        int row = f * 4 + g;
        ws[WS_WT + c * 192 + row] = v;
        ws[WS_W2 + row * 128 + c] = v;
    }
    if (tid < F_) {
        const int f = tid;
        // L1 row normalization (axis=2 of Q_param[f,g,l])
        float Qm[4][4];
        for (int g = 0; g < 4; ++g) {
            float s = 0.f;
            for (int l = 0; l < 4; ++l) s += fabsf(Qp[f * 16 + g * 4 + l]);
            float d = fmaxf(s, 1.0f);
            for (int l = 0; l < 4; ++l) Qm[g][l] = Qp[f * 16 + g * 4 + l] / d;
        }
        // A = Q^T Q (4x4 SPD); lambda_max(A) = sigma_max(Q)^2
        double A[4][4];
        for (int i = 0; i < 4; ++i)
            for (int j = 0; j < 4; ++j) {
                double s = 0.0;
                for (int g = 0; g < 4; ++g) s += (double)Qm[g][i] * (double)Qm[g][j];
                A[i][j] = s;
            }
        double M[4][4];
        for (int i = 0; i < 4; ++i) for (int j = 0; j < 4; ++j) M[i][j] = A[i][j];
        for (int it = 0; it < 30; ++it) {
            double T[4][4]; double mx = 0.0;
            for (int i = 0; i < 4; ++i)
                for (int j = 0; j < 4; ++j) {
                    double s = 0.0;
                    for (int k = 0; k < 4; ++k) s += M[i][k] * M[k][j];
                    T[i][j] = s;
                    double a = fabs(s); if (a > mx) mx = a;
                }
            if (mx < 1e-300) break;
            double inv = 1.0 / mx;
            for (int i = 0; i < 4; ++i) for (int j = 0; j < 4; ++j) M[i][j] = T[i][j] * inv;
        }
        int jb = 0; double bn = -1.0;
        for (int j = 0; j < 4; ++j) {
            double n = 0.0;
            for (int i = 0; i < 4; ++i) n += M[i][j] * M[i][j];
            if (n > bn) { bn = n; jb = j; }
        }
        double v[4]; for (int i = 0; i < 4; ++i) v[i] = M[i][jb];
        double Av[4];
        for (int i = 0; i < 4; ++i) {
            double s = 0.0;
            for (int j = 0; j < 4; ++j) s += A[i][j] * v[j];
            Av[i] = s;
        }
        double vv = 0.0, vav = 0.0;
        for (int i = 0; i < 4; ++i) { vv += v[i] * v[i]; vav += v[i] * Av[i]; }
        double lam = (vv > 0.0) ? (vav / vv) : 0.0;
        float lamf = (float)lam;
        for (int l = 0; l < 4; ++l)
            for (int g = 0; g < 4; ++g)
                ws[WS_QE + f * 16 + l * 4 + g] = Qm[l][g] / lamf;
        for (int g = 0; g < 4; ++g)
            for (int l = 0; l < 4; ++l)
                ws[WS_QN + f * 16 + g * 4 + l] = Qm[g][l];
        float tau = expf(fmaxf(taus_p[f], 0.0f));
        ws[WS_QS + f] = SCALE_C / tau;
    }
    if (tid == 0) {
        float lamb_e = expf(lamb[0]);
        float eps_e  = expf(eps_om[0]);
        ws[WS_MISC + 0] = lamb_e;
        ws[WS_MISC + 1] = eps_e;
        ws[WS_MISC + 2] = 1.0f / (1.0f + lamb_e * (1.0f + eps_e));
        for (int b = 0; b < 2; ++b) {
            float sg = sigma[b];
            float t = sg * 20.0f - 2.0f;
            float h1[F_], h2[F_];
            for (int j = 0; j < F_; ++j) h1[j] = fmaxf(t * mw1[j] + mb1[j], 0.0f);
            for (int j = 0; j < F_; ++j) {
                float s = mb2[j];
                for (int k = 0; k < F_; ++k) s += h1[k] * mw2[k * F_ + j];
                h2[j] = fmaxf(s, 0.0f);
            }
            for (int j = 0; j < F_; ++j) {
                float s = mb3[j];
                for (int k = 0; k < F_; ++k) s += h2[k] * mw3[k * F_ + j];
                float sc = fmaxf(s * 0.05f + sg, 0.0f) * 1.0f + 1e-9f;
                ws[WS_SCAL + b * F_ + j] = sc;
                ws[WS_ISCAL + b * F_ + j] = 1.0f / sc;
            }
        }
    }
}

__device__ __forceinline__ v2f vfma(v2f a, v2f b, v2f c) {
#if __has_builtin(__builtin_elementwise_fma)
    return __builtin_elementwise_fma(a, b, c);
#else
    return (v2f){fmaf(a.x, b.x, c.x), fmaf(a.y, b.y, c.y)};
#endif
}

__device__ __forceinline__ void loadrow(v2f* __restrict__ w, const float* __restrict__ base) {
    const v2f* p = reinterpret_cast<const v2f*>(base);
#pragma unroll
    for (int j = 0; j < 16; ++j) w[j] = p[j];
}

__device__ __forceinline__ float dot32(const v2f* __restrict__ w, const v2f* __restrict__ x) {
    v2f a0 = w[0] * x[0];
    v2f a1 = w[1] * x[1];
    v2f a2 = w[2] * x[2];
    v2f a3 = w[3] * x[3];
#pragma unroll
    for (int j = 4; j < 16; j += 4) {
        a0 = vfma(w[j + 0], x[j + 0], a0);
        a1 = vfma(w[j + 1], x[j + 1], a1);
        a2 = vfma(w[j + 2], x[j + 2], a2);
        a3 = vfma(w[j + 3], x[j + 3], a3);
    }
    v2f s = (a0 + a1) + (a2 + a3);
    return s.x + s.y;
}

__device__ __forceinline__ void axpy32(v2f* __restrict__ go, const v2f* __restrict__ w, float a) {
    v2f av = {a, a};
#pragma unroll
    for (int j = 0; j < 16; ++j) go[j] = vfma(w[j], av, go[j]);
}

// Euclidean projection of a 4-vector onto the unit l1 ball (per lane, in regs)
__device__ __forceinline__ void proj4(const float v[4], float o[4]) {
    float a0 = fabsf(v[0]), a1 = fabsf(v[1]), a2 = fabsf(v[2]), a3 = fabsf(v[3]);
    float sum = a0 + a1 + a2 + a3;
    float t0 = fmaxf(a0, a1), u0 = fminf(a0, a1);
    float t1 = fmaxf(a2, a3), u1 = fminf(a2, a3);
    float s0 = fmaxf(t0, t1), m0 = fminf(t0, t1);
    float m1 = fmaxf(u0, u1), s3 = fminf(u0, u1);
    float s1 = fmaxf(m1, m0), s2 = fminf(m1, m0);
    float c2 = s0 + s1, c3 = c2 + s2, c4 = c3 + s3;
    float th = s0 - 1.0f, rh = 1.0f;
    if (s1 * 2.0f > c2 - 1.0f) { th = c2 - 1.0f; rh = 2.0f; }
    if (s2 * 3.0f > c3 - 1.0f) { th = c3 - 1.0f; rh = 3.0f; }
    if (s3 * 4.0f > c4 - 1.0f) { th = c4 - 1.0f; rh = 4.0f; }
    float theta = fmaxf(th / rh, 0.0f);
    bool inside = (sum <= 1.0f);
#pragma unroll
    for (int g = 0; g < 4; ++g) {
        float ag = fabsf(v[g]);
        float pg = copysignf(fmaxf(ag - theta, 0.0f), v[g]);
        o[g] = inside ? v[g] : pg;
    }
}

// Register-resident main kernel.
// Wave = 16 pixels x 4 channel-chunks (32 ch each). Block = 4 waves = 64 pixels.
// x, x_noisy, accumulator all live in VGPRs; weights stream from L2 as vector
// loads (vmcnt); cross-chunk reduction via 2 shfl_xor. Zero LDS.
__global__ __launch_bounds__(TPB, 2) void mfoe_main(
    const float* __restrict__ xnoisy,
    const float* __restrict__ ws,
    float* __restrict__ out,
    const int* __restrict__ n_iter_p)
{
    const int tid   = threadIdx.x;
    const int lane  = tid & 63;
    const int wv    = tid >> 6;          // wave in block, 0..3
    const int p     = lane & 15;         // pixel within wave
    const int chunk = lane >> 4;         // channel chunk, 0..3
    const int c0    = chunk * 32;
    const int blk   = blockIdx.x;
    const int b     = blk >> 8;          // image index (256 blocks per image)
    const int pix   = ((blk & 255) << 6) + (wv << 4) + p;

    const float* __restrict__ xin  = xnoisy + b * (C_ * HW) + pix;
    float* __restrict__       oimg = out    + b * (C_ * HW) + pix;

    const float lamb_e = ws[WS_MISC + 0];
    const float eps_e  = ws[WS_MISC + 1];
    const float invden = ws[WS_MISC + 2];
    const int   niter  = *n_iter_p;

    v2f xr[16], xn[16], go[16];
#pragma unroll
    for (int i = 0; i < 16; ++i) {
        float lo = xin[(c0 + 2 * i) * HW];
        float hi = xin[(c0 + 2 * i + 1) * HW];
        xn[i] = (v2f){lo, hi};
        xr[i] = xn[i];
    }

    const float* __restrict__ W2 = ws + WS_W2;

    for (int it = 0; it < niter; ++it) {
#pragma unroll
        for (int i = 0; i < 16; ++i) go[i] = (v2f){0.0f, 0.0f};

#pragma unroll 1
        for (int f = 0; f < F_; ++f) {
            const float* Wbase = W2 + (f * 4) * 128 + c0;
            v2f wa[16], wb[16];

            // ---- pass 1: partial dots over this lane's 32 channels
            loadrow(wa, Wbase);
            loadrow(wb, Wbase + 128);
            float d0 = dot32(wa, xr);
            loadrow(wa, Wbase + 256);
            float d1 = dot32(wb, xr);
            loadrow(wb, Wbase + 384);
            float d2 = dot32(wa, xr);
            float d3 = dot32(wb, xr);

            // cross-chunk butterfly reduce (lanes p, p+16, p+32, p+48)
            d0 += __shfl_xor(d0, 16); d0 += __shfl_xor(d0, 32);
            d1 += __shfl_xor(d1, 16); d1 += __shfl_xor(d1, 32);
            d2 += __shfl_xor(d2, 16); d2 += __shfl_xor(d2, 32);
            d3 += __shfl_xor(d3, 16); d3 += __shfl_xor(d3, 32);

            // ---- activation (redundant across the 4 chunk groups, all in regs)
            const float invs = ws[WS_ISCAL + b * F_ + f];
            const float scl  = ws[WS_SCAL  + b * F_ + f];
            const float qsv  = ws[WS_QS + f];
            const float* qe = ws + WS_QE + f * 16;
            const float* qn = ws + WS_QN + f * 16;
            float v[4] = {d0 * invs, d1 * invs, d2 * invs, d3 * invs};
            float pv[4]; proj4(v, pv);
            float y[4];
#pragma unroll
            for (int l = 0; l < 4; ++l)
                y[l] = qsv * (qe[l*4+0]*v[0] + qe[l*4+1]*v[1] + qe[l*4+2]*v[2] + qe[l*4+3]*v[3]);
            float py[4]; proj4(y, py);
            float m2[4];
#pragma unroll
            for (int g = 0; g < 4; ++g) m2[g] = fmaf(eps_e, y[g], py[g]);
            float act[4];
#pragma unroll
            for (int l = 0; l < 4; ++l) {
                float gcc = SCALE_C * (qn[0*4+l]*m2[0] + qn[1*4+l]*m2[1] +
                                       qn[2*4+l]*m2[2] + qn[3*4+l]*m2[3]);
                float gc = fmaf(eps_e, v[l], pv[l]);
                act[l] = lamb_e * (gc - gcc) * scl;
            }

            // ---- pass 2: scatter into this lane's 32-channel accumulator
            loadrow(wa, Wbase);
            loadrow(wb, Wbase + 128);
            axpy32(go, wa, act[0]);
            loadrow(wa, Wbase + 256);
            axpy32(go, wb, act[1]);
            loadrow(wb, Wbase + 384);
            axpy32(go, wa, act[2]);
            axpy32(go, wb, act[3]);
        }

        // ---- update (fully thread-local)
        v2f dv = {invden, invden};
#pragma unroll
        for (int i = 0; i < 16; ++i) {
            v2f t = (xr[i] - xn[i]) + go[i];
            xr[i] = xr[i] - t * dv;
        }
    }

#pragma unroll
    for (int i = 0; i < 16; ++i) {
        oimg[(c0 + 2 * i) * HW]     = xr[i].x;
        oimg[(c0 + 2 * i + 1) * HW] = xr[i].y;
    }
}

extern "C" void kernel_launch(void* const* d_in, const int* in_sizes, int n_in,
                              void* d_out, int out_size, void* d_ws, size_t ws_size,
                              hipStream_t stream) {
    const float* x_noisy = (const float*)d_in[0];
    const float* sigma   = (const float*)d_in[1];
    const float* Qp      = (const float*)d_in[2];
    const float* taus_p  = (const float*)d_in[3];
    const float* lamb    = (const float*)d_in[4];
    const float* eps_om  = (const float*)d_in[5];
    const float* mw1     = (const float*)d_in[6];
    const float* mb1     = (const float*)d_in[7];
    const float* mw2     = (const float*)d_in[8];
    const float* mb2     = (const float*)d_in[9];
    const float* mw3     = (const float*)d_in[10];
    const float* mb3     = (const float*)d_in[11];
    const float* Wf      = (const float*)d_in[12];
    const int*   n_iter  = (const int*)d_in[13];
    float* out = (float*)d_out;
    float* ws  = (float*)d_ws;

    hipLaunchKernelGGL(setup_kernel, dim3(1), dim3(TPB), 0, stream,
                       sigma, Qp, taus_p, lamb, eps_om,
                       mw1, mb1, mw2, mb2, mw3, mb3, Wf, ws);
    hipLaunchKernelGGL(mfoe_main, dim3(512), dim3(TPB), 0, stream,
                       x_noisy, ws, out, n_iter);
}

// Round 3
// 407.598 us; speedup vs baseline: 3.0641x; 3.0641x over previous
//
#include <hip/hip_runtime.h>
#include <math.h>

#define F_ 48
#define C_ 128
#define HW 16384
#define SCALE_C 0.999f
#define TPB 256

typedef __attribute__((ext_vector_type(8))) short short8;
typedef __attribute__((ext_vector_type(4))) float floatx4;

// ---- ws layout ----
// ushort region (fragments):
//   P1 frags: [b(2)][hl(2)][mt(12)][ks(4)][lane(64)][j(8)]  = 98304 ushorts
//   P2 frags: [b(2)][hl(2)][cmt(8)][ks(6)][lane(64)][j(8)] = 98304 ushorts
// float region (params), starting at float offset 98304 (= 393216 bytes):
//   QEQN: [48][32]  (qeS[l*4+g] premul by SCALE/(tau*lamf); qnS[16+g*4+l] premul SCALE)
//   MISC: [eps_e, invden]
#define P1_U 0
#define P2_U 98304
#define QEQN_F 98304
#define MISC_F (QEQN_F + 48 * 32)

// LDS strides (bf16 units). Chosen so (row_stride_bytes/4) mod 32 = 12 -> 2-way
// bank aliasing (free, m136) and 16B alignment for ds_read_b128.
#define XS 152     // x rows: 128 channels + pad  (304 B/row)
#define AS 104     // act rows: 96 local rows + pad (208 B/row)

__device__ __forceinline__ unsigned short f2bf(float f) {
    unsigned u = __float_as_uint(f);
    unsigned r = u + 0x7fffu + ((u >> 16) & 1u);
    return (unsigned short)(r >> 16);
}
__device__ __forceinline__ float bf2f(unsigned short h) {
    return __uint_as_float(((unsigned)h) << 16);
}

__global__ void setup_kernel(const float* __restrict__ sigma,
                             const float* __restrict__ Qp,
                             const float* __restrict__ taus_p,
                             const float* __restrict__ lamb,
                             const float* __restrict__ eps_om,
                             const float* __restrict__ mw1, const float* __restrict__ mb1,
                             const float* __restrict__ mw2, const float* __restrict__ mb2,
                             const float* __restrict__ mw3, const float* __restrict__ mb3,
                             const float* __restrict__ Wf,
                             float* __restrict__ wsf)
{
    __shared__ float sInv[2][F_];      // 1/scaling per (b,f)  -> folded into P1
    __shared__ float sSclLam[2][F_];   // lamb_e*scaling       -> folded into P2
    const int tid = threadIdx.x;
    unsigned short* wsu = (unsigned short*)wsf;

    if (tid < F_) {
        const int f = tid;
        // L1 row normalization over axis2 (l)
        float Qm[4][4];
        for (int g = 0; g < 4; ++g) {
            float s = 0.f;
            for (int l = 0; l < 4; ++l) s += fabsf(Qp[f * 16 + g * 4 + l]);
            float d = fmaxf(s, 1.0f);
            for (int l = 0; l < 4; ++l) Qm[g][l] = Qp[f * 16 + g * 4 + l] / d;
        }
        // sigma_max(Q)^2 = lambda_max(Q^T Q) via normalized repeated squaring
        double A[4][4];
        for (int i = 0; i < 4; ++i)
            for (int j = 0; j < 4; ++j) {
                double s = 0.0;
                for (int g = 0; g < 4; ++g) s += (double)Qm[g][i] * (double)Qm[g][j];
                A[i][j] = s;
            }
        double M[4][4];
        for (int i = 0; i < 4; ++i) for (int j = 0; j < 4; ++j) M[i][j] = A[i][j];
        for (int it = 0; it < 30; ++it) {
            double T[4][4]; double mx = 0.0;
            for (int i = 0; i < 4; ++i)
                for (int j = 0; j < 4; ++j) {
                    double s = 0.0;
                    for (int k = 0; k < 4; ++k) s += M[i][k] * M[k][j];
                    T[i][j] = s;
                    double a = fabs(s); if (a > mx) mx = a;
                }
            if (mx < 1e-300) break;
            double inv = 1.0 / mx;
            for (int i = 0; i < 4; ++i) for (int j = 0; j < 4; ++j) M[i][j] = T[i][j] * inv;
        }
        int jb = 0; double bn = -1.0;
        for (int j = 0; j < 4; ++j) {
            double nn = 0.0;
            for (int i = 0; i < 4; ++i) nn += M[i][j] * M[i][j];
            if (nn > bn) { bn = nn; jb = j; }
        }
        double v[4]; for (int i = 0; i < 4; ++i) v[i] = M[i][jb];
        double Av[4];
        for (int i = 0; i < 4; ++i) {
            double s = 0.0;
            for (int j = 0; j < 4; ++j) s += A[i][j] * v[j];
            Av[i] = s;
        }
        double vv = 0.0, vav = 0.0;
        for (int i = 0; i < 4; ++i) { vv += v[i] * v[i]; vav += v[i] * Av[i]; }
        float lamf = (float)((vv > 0.0) ? (vav / vv) : 0.0);
        float tau = expf(fmaxf(taus_p[f], 0.0f));
        float qsv = SCALE_C / tau;
        for (int l = 0; l < 4; ++l)
            for (int g = 0; g < 4; ++g)
                wsf[QEQN_F + f * 32 + l * 4 + g] = qsv * Qm[l][g] / lamf;
        for (int g = 0; g < 4; ++g)
            for (int l = 0; l < 4; ++l)
                wsf[QEQN_F + f * 32 + 16 + g * 4 + l] = SCALE_C * Qm[g][l];
    }
    if (tid < 2) {
        const int b = tid;
        float lamb_e = expf(lamb[0]);
        float sg = sigma[b];
        float t = sg * 20.0f - 2.0f;
        float h1[F_], h2[F_];
        for (int j = 0; j < F_; ++j) h1[j] = fmaxf(t * mw1[j] + mb1[j], 0.0f);
        for (int j = 0; j < F_; ++j) {
            float s = mb2[j];
            for (int k = 0; k < F_; ++k) s += h1[k] * mw2[k * F_ + j];
            h2[j] = fmaxf(s, 0.0f);
        }
        for (int j = 0; j < F_; ++j) {
            float s = mb3[j];
            for (int k = 0; k < F_; ++k) s += h2[k] * mw3[k * F_ + j];
            float sc = fmaxf(s * 0.05f + sg, 0.0f) + 1e-9f;
            sInv[b][j] = 1.0f / sc;
            sSclLam[b][j] = lamb_e * sc;
        }
    }
    if (tid == 2) {
        float lamb_e = expf(lamb[0]);
        float eps_e = expf(eps_om[0]);
        wsf[MISC_F + 0] = eps_e;
        wsf[MISC_F + 1] = 1.0f / (1.0f + lamb_e * (1.0f + eps_e));
    }
    __syncthreads();

    // ---- pack pass-1 A fragments (M=row r, K=channel c), invs folded per b
    for (int idx = tid; idx < 12 * 4 * 64 * 8; idx += TPB) {
        int j = idx & 7, lane = (idx >> 3) & 63;
        int t = idx >> 9;               // 0..47
        int ks = t & 3, mt = t >> 2;    // mt 0..11
        int m = lane & 15, q = lane >> 4;
        int r = mt * 16 + m;
        int c = ks * 32 + q * 8 + j;
        int f = r >> 2, g = r & 3;
        float w = Wf[(g * F_ + f) * C_ + c];
        for (int b = 0; b < 2; ++b) {
            float v = w * sInv[b][f];
            unsigned short h = f2bf(v);
            unsigned short l = f2bf(v - bf2f(h));
            wsu[P1_U + ((((b * 2 + 0) * 12 + mt) * 4 + ks) * 64 + lane) * 8 + j] = h;
            wsu[P1_U + ((((b * 2 + 1) * 12 + mt) * 4 + ks) * 64 + lane) * 8 + j] = l;
        }
    }
    // ---- pack pass-2 A fragments (M=channel c, K=row r), lamb_e*scl folded per b
    for (int idx = tid; idx < 8 * 6 * 64 * 8; idx += TPB) {
        int j = idx & 7, lane = (idx >> 3) & 63;
        int t = idx >> 9;                 // 0..47
        int ks = t % 6, cmt = t / 6;      // cmt 0..7
        int m = lane & 15, q = lane >> 4;
        int cch = cmt * 16 + m;
        int r = ks * 32 + q * 8 + j;
        int f = r >> 2, g = r & 3;
        float w = Wf[(g * F_ + f) * C_ + cch];
        for (int b = 0; b < 2; ++b) {
            float v = w * sSclLam[b][f];
            unsigned short h = f2bf(v);
            unsigned short l = f2bf(v - bf2f(h));
            wsu[P2_U + ((((b * 2 + 0) * 8 + cmt) * 6 + ks) * 64 + lane) * 8 + j] = h;
            wsu[P2_U + ((((b * 2 + 1) * 8 + cmt) * 6 + ks) * 64 + lane) * 8 + j] = l;
        }
    }
}

// Euclidean projection of a 4-vector onto the unit l1 ball (per lane, in regs)
__device__ __forceinline__ void proj4(const float v[4], float o[4]) {
    float a0 = fabsf(v[0]), a1 = fabsf(v[1]), a2 = fabsf(v[2]), a3 = fabsf(v[3]);
    float sum = a0 + a1 + a2 + a3;
    float t0 = fmaxf(a0, a1), u0 = fminf(a0, a1);
    float t1 = fmaxf(a2, a3), u1 = fminf(a2, a3);
    float s0 = fmaxf(t0, t1), m0 = fminf(t0, t1);
    float m1 = fmaxf(u0, u1), s3 = fminf(u0, u1);
    float s1 = fmaxf(m1, m0), s2 = fminf(m1, m0);
    float c2 = s0 + s1, c3 = c2 + s2, c4 = c3 + s3;
    float th = s0 - 1.0f, rh = 1.0f;
    if (s1 * 2.0f > c2 - 1.0f) { th = c2 - 1.0f; rh = 2.0f; }
    if (s2 * 3.0f > c3 - 1.0f) { th = c3 - 1.0f; rh = 3.0f; }
    if (s3 * 4.0f > c4 - 1.0f) { th = c4 - 1.0f; rh = 4.0f; }
    float theta = fmaxf(th / rh, 0.0f);
    bool inside = (sum <= 1.0f);
#pragma unroll
    for (int g = 0; g < 4; ++g) {
        float ag = fabsf(v[g]);
        float pg = copysignf(fmaxf(ag - theta, 0.0f), v[g]);
        o[g] = inside ? v[g] : pg;
    }
}

// MFMA main kernel. Block = 4 waves = 64-pixel tile.
// Pass1: Lx = P1frag @ x   (M=192 rows, K=128 ch)  -> activation in MFMA D-regs
// Pass2: go = P2frag @ act (M=128 ch,  K=192 rows) -> x update
// x kept in LDS as bf16 hi/lo pair; act as single bf16 (row-halves of 96).
__global__ __launch_bounds__(TPB, 2) void mfoe_main(
    const float* __restrict__ xnoisy,
    const float* __restrict__ wsf,
    float* __restrict__ out,
    const int* __restrict__ n_iter_p)
{
    __shared__ __align__(16) unsigned short sXH[64 * XS];
    __shared__ __align__(16) unsigned short sXL[64 * XS];
    __shared__ __align__(16) unsigned short sACT[64 * AS];

    const int tid = threadIdx.x;
    const int lane = tid & 63;
    const int wv = tid >> 6;       // wave 0..3
    const int n = lane & 15;       // pixel-within-tile / M-frag index
    const int q = lane >> 4;       // quad 0..3
    const int blk = blockIdx.x;
    const int b = blk >> 8;
    const int pix0 = (blk & 255) << 6;

    const float* __restrict__ xin = xnoisy + b * (C_ * HW) + pix0;
    float* __restrict__ oimg = out + b * (C_ * HW) + pix0;
    const unsigned short* __restrict__ wsu = (const unsigned short*)wsf;
    const int niter = *n_iter_p;

    if (niter == 0) {
        for (int i = tid; i < C_ * 64; i += TPB) {
            int p = i & 63, c = i >> 6;
            oimg[c * HW + p] = xin[c * HW + p];
        }
        return;
    }

    // stage x -> LDS bf16 hi/lo (coalesced reads)
    for (int i = tid; i < C_ * 64; i += TPB) {
        int p = i & 63, c = i >> 6;
        float v = xin[c * HW + p];
        unsigned short h = f2bf(v);
        sXH[p * XS + c] = h;
        sXL[p * XS + c] = f2bf(v - bf2f(h));
    }

    // preload this thread's x_noisy values for the update jobs
    float xnr[32];
#pragma unroll
    for (int j = 0; j < 8; ++j) {
        int jw = wv * 8 + j, cmt = jw >> 2, nt = jw & 3;
        int p = nt * 16 + n;
#pragma unroll
        for (int reg = 0; reg < 4; ++reg) {
            int c = cmt * 16 + q * 4 + reg;
            xnr[j * 4 + reg] = xin[c * HW + p];
        }
    }
    const float eps_e = wsf[MISC_F + 0];
    const float invden = wsf[MISC_F + 1];

    for (int it = 0; it < niter; ++it) {
        floatx4 acc2[8];
#pragma unroll
        for (int j = 0; j < 8; ++j) acc2[j] = (floatx4){0.f, 0.f, 0.f, 0.f};

#pragma unroll 1
        for (int h = 0; h < 2; ++h) {
            __syncthreads();   // x ready / act buffer free
            // ---- pass 1: 24 (mtile,ntile) jobs per half, 6 per wave
#pragma unroll 1
            for (int j = 0; j < 6; ++j) {
                int jw = wv * 6 + j, mtl = jw >> 2, nt = jw & 3;
                int mt = h * 6 + mtl;
                int p = nt * 16 + n;
                floatx4 acc = (floatx4){0.f, 0.f, 0.f, 0.f};
                const short8* aHp = (const short8*)(wsu + P1_U + (((b * 2 + 0) * 12 + mt) * 4) * 512 + lane * 8);
                const short8* aLp = (const short8*)(wsu + P1_U + (((b * 2 + 1) * 12 + mt) * 4) * 512 + lane * 8);
#pragma unroll
                for (int ks = 0; ks < 4; ++ks) {
                    short8 aH = aHp[ks * 64];
                    short8 aL = aLp[ks * 64];
                    short8 bH = *(const short8*)&sXH[p * XS + ks * 32 + q * 8];
                    short8 bL = *(const short8*)&sXL[p * XS + ks * 32 + q * 8];
                    acc = __builtin_amdgcn_mfma_f32_16x16x32_bf16(aH, bH, acc, 0, 0, 0);
                    acc = __builtin_amdgcn_mfma_f32_16x16x32_bf16(aH, bL, acc, 0, 0, 0);
                    acc = __builtin_amdgcn_mfma_f32_16x16x32_bf16(aL, bH, acc, 0, 0, 0);
                }
                // ---- activation entirely in D-regs: lane owns (f = h*24+mtl*4+q, pixel p)
                int f = h * 24 + mtl * 4 + q;
                const float* qp = wsf + QEQN_F + f * 32;
                float v[4] = {acc[0], acc[1], acc[2], acc[3]};
                float pv[4]; proj4(v, pv);
                float y[4];
#pragma unroll
                for (int l = 0; l < 4; ++l)
                    y[l] = fmaf(qp[l * 4 + 0], v[0], fmaf(qp[l * 4 + 1], v[1],
                           fmaf(qp[l * 4 + 2], v[2], qp[l * 4 + 3] * v[3])));
                float py[4]; proj4(y, py);
                float m2[4];
#pragma unroll
                for (int g = 0; g < 4; ++g) m2[g] = fmaf(eps_e, y[g], py[g]);
                unsigned long long pk = 0ull;
#pragma unroll
                for (int l = 0; l < 4; ++l) {
                    float gcc = fmaf(qp[16 + 0 + l], m2[0], fmaf(qp[16 + 4 + l], m2[1],
                                fmaf(qp[16 + 8 + l], m2[2], qp[16 + 12 + l] * m2[3])));
                    float av = fmaf(eps_e, v[l], pv[l]) - gcc;   // unscaled act
                    pk |= ((unsigned long long)f2bf(av)) << (16 * l);
                }
                *(unsigned long long*)&sACT[p * AS + mtl * 16 + q * 4] = pk;
            }
            __syncthreads();   // act ready
            // ---- pass 2 partial: 32 (ctile,ntile) jobs, 8 per wave, K = this half's 96 rows
#pragma unroll
            for (int j = 0; j < 8; ++j) {
                int jw = wv * 8 + j, cmt = jw >> 2, nt = jw & 3;
                int p = nt * 16 + n;
                const short8* a2H = (const short8*)(wsu + P2_U + (((b * 2 + 0) * 8 + cmt) * 6 + h * 3) * 512 + lane * 8);
                const short8* a2L = (const short8*)(wsu + P2_U + (((b * 2 + 1) * 8 + cmt) * 6 + h * 3) * 512 + lane * 8);
                floatx4 a = acc2[j];
#pragma unroll
                for (int ksl = 0; ksl < 3; ++ksl) {
                    short8 aH = a2H[ksl * 64];
                    short8 aL = a2L[ksl * 64];
                    short8 bA = *(const short8*)&sACT[p * AS + ksl * 32 + q * 8];
                    a = __builtin_amdgcn_mfma_f32_16x16x32_bf16(aH, bA, a, 0, 0, 0);
                    a = __builtin_amdgcn_mfma_f32_16x16x32_bf16(aL, bA, a, 0, 0, 0);
                }
                acc2[j] = a;
            }
        }
        // ---- update: lane owns channels cmt*16+q*4..+3 at pixel p (disjoint across threads)
        const bool last = (it == niter - 1);
#pragma unroll
        for (int j = 0; j < 8; ++j) {
            int jw = wv * 8 + j, cmt = jw >> 2, nt = jw & 3;
            int p = nt * 16 + n;
            int cb = cmt * 16 + q * 4;
            unsigned long long oh = *(const unsigned long long*)&sXH[p * XS + cb];
            unsigned long long ol = *(const unsigned long long*)&sXL[p * XS + cb];
            unsigned long long nh = 0ull, nl = 0ull;
#pragma unroll
            for (int reg = 0; reg < 4; ++reg) {
                float xo = bf2f((unsigned short)(oh >> (16 * reg))) +
                           bf2f((unsigned short)(ol >> (16 * reg)));
                float nx = xo - (xo - xnr[j * 4 + reg] + acc2[j][reg]) * invden;
                if (last) oimg[(cb + reg) * HW + p] = nx;
                unsigned short hh = f2bf(nx);
                nh |= ((unsigned long long)hh) << (16 * reg);
                nl |= ((unsigned long long)f2bf(nx - bf2f(hh))) << (16 * reg);
            }
            *(unsigned long long*)&sXH[p * XS + cb] = nh;
            *(unsigned long long*)&sXL[p * XS + cb] = nl;
        }
    }
}

extern "C" void kernel_launch(void* const* d_in, const int* in_sizes, int n_in,
                              void* d_out, int out_size, void* d_ws, size_t ws_size,
                              hipStream_t stream) {
    const float* x_noisy = (const float*)d_in[0];
    const float* sigma   = (const float*)d_in[1];
    const float* Qp      = (const float*)d_in[2];
    const float* taus_p  = (const float*)d_in[3];
    const float* lamb    = (const float*)d_in[4];
    const float* eps_om  = (const float*)d_in[5];
    const float* mw1     = (const float*)d_in[6];
    const float* mb1     = (const float*)d_in[7];
    const float* mw2     = (const float*)d_in[8];
    const float* mb2     = (const float*)d_in[9];
    const float* mw3     = (const float*)d_in[10];
    const float* mb3     = (const float*)d_in[11];
    const float* Wf      = (const float*)d_in[12];
    const int*   n_iter  = (const int*)d_in[13];
    float* out = (float*)d_out;
    float* ws  = (float*)d_ws;

    hipLaunchKernelGGL(setup_kernel, dim3(1), dim3(TPB), 0, stream,
                       sigma, Qp, taus_p, lamb, eps_om,
                       mw1, mb1, mw2, mb2, mw3, mb3, Wf, ws);
    hipLaunchKernelGGL(mfoe_main, dim3(512), dim3(TPB), 0, stream,
                       x_noisy, ws, out, n_iter);
}

// Round 4
// 333.266 us; speedup vs baseline: 3.7475x; 1.2230x over previous
//
#include <hip/hip_runtime.h>
#include <math.h>

#define F_ 48
#define C_ 128
#define HW 16384
#define SCALE_C 0.999f
#define TPB 256

typedef __attribute__((ext_vector_type(8))) short short8;
typedef __attribute__((ext_vector_type(4))) float floatx4;

// ---- ws layout ----
// ushort region (fragments):
//   P1 frags: [b(2)][hl(2)][mt(12)][ks(4)][lane(64)][j(8)]  = 98304 ushorts
//   P2 frags: [b(2)][hl(2)][cmt(8)][ks(6)][lane(64)][j(8)]  = 98304 ushorts
// float region at float offset 98304 (byte 393216):
#define P1_U 0
#define P2_U 98304
#define QEQN_F 98304              // [48][32]
#define MISC_F (QEQN_F + 1536)    // eps_e, invden
#define SINV_F (MISC_F + 2)       // [2][48] 1/scaling
#define SLAM_F (SINV_F + 96)      // [2][48] lamb_e*scaling

// LDS strides (bf16 units); XS: 76 dwords/row == 12 mod 32; AS: 52 == 20 mod 32.
#define XS 152
#define AS 104
#define QS 36    // sQ row stride in floats (16B-aligned, 2-way bank alias = free)

__device__ __forceinline__ unsigned short f2bf(float f) {     // RTNE
    unsigned u = __float_as_uint(f);
    unsigned r = u + 0x7fffu + ((u >> 16) & 1u);
    return (unsigned short)(r >> 16);
}
__device__ __forceinline__ float bf2f(unsigned short h) {
    return __uint_as_float(((unsigned)h) << 16);
}

// ---------------- setup: math (1 block, tiny) ----------------
__global__ void setup_math(const float* __restrict__ sigma,
                           const float* __restrict__ Qp,
                           const float* __restrict__ taus_p,
                           const float* __restrict__ lamb,
                           const float* __restrict__ eps_om,
                           const float* __restrict__ mw1, const float* __restrict__ mb1,
                           const float* __restrict__ mw2, const float* __restrict__ mb2,
                           const float* __restrict__ mw3, const float* __restrict__ mb3,
                           float* __restrict__ wsf)
{
    const int tid = threadIdx.x;
    if (tid < F_) {
        const int f = tid;
        float Qm[4][4];
        for (int g = 0; g < 4; ++g) {
            float s = 0.f;
            for (int l = 0; l < 4; ++l) s += fabsf(Qp[f * 16 + g * 4 + l]);
            float d = fmaxf(s, 1.0f);
            for (int l = 0; l < 4; ++l) Qm[g][l] = Qp[f * 16 + g * 4 + l] / d;
        }
        double A[4][4];
        for (int i = 0; i < 4; ++i)
            for (int j = 0; j < 4; ++j) {
                double s = 0.0;
                for (int g = 0; g < 4; ++g) s += (double)Qm[g][i] * (double)Qm[g][j];
                A[i][j] = s;
            }
        double M[4][4];
        for (int i = 0; i < 4; ++i) for (int j = 0; j < 4; ++j) M[i][j] = A[i][j];
        for (int it = 0; it < 30; ++it) {
            double T[4][4]; double mx = 0.0;
            for (int i = 0; i < 4; ++i)
                for (int j = 0; j < 4; ++j) {
                    double s = 0.0;
                    for (int k = 0; k < 4; ++k) s += M[i][k] * M[k][j];
                    T[i][j] = s;
                    double a = fabs(s); if (a > mx) mx = a;
                }
            if (mx < 1e-300) break;
            double inv = 1.0 / mx;
            for (int i = 0; i < 4; ++i) for (int j = 0; j < 4; ++j) M[i][j] = T[i][j] * inv;
        }
        int jb = 0; double bn = -1.0;
        for (int j = 0; j < 4; ++j) {
            double nn = 0.0;
            for (int i = 0; i < 4; ++i) nn += M[i][j] * M[i][j];
            if (nn > bn) { bn = nn; jb = j; }
        }
        double v[4]; for (int i = 0; i < 4; ++i) v[i] = M[i][jb];
        double Av[4];
        for (int i = 0; i < 4; ++i) {
            double s = 0.0;
            for (int j = 0; j < 4; ++j) s += A[i][j] * v[j];
            Av[i] = s;
        }
        double vv = 0.0, vav = 0.0;
        for (int i = 0; i < 4; ++i) { vv += v[i] * v[i]; vav += v[i] * Av[i]; }
        float lamf = (float)((vv > 0.0) ? (vav / vv) : 0.0);
        float tau = expf(fmaxf(taus_p[f], 0.0f));
        float qsv = SCALE_C / tau;
        for (int l = 0; l < 4; ++l)
            for (int g = 0; g < 4; ++g)
                wsf[QEQN_F + f * 32 + l * 4 + g] = qsv * Qm[l][g] / lamf;
        for (int g = 0; g < 4; ++g)
            for (int l = 0; l < 4; ++l)
                wsf[QEQN_F + f * 32 + 16 + g * 4 + l] = SCALE_C * Qm[g][l];
    }
    if (tid >= 48 && tid < 50) {
        const int b = tid - 48;
        float lamb_e = expf(lamb[0]);
        float sg = sigma[b];
        float t = sg * 20.0f - 2.0f;
        float h1[F_], h2[F_];
        for (int j = 0; j < F_; ++j) h1[j] = fmaxf(t * mw1[j] + mb1[j], 0.0f);
        for (int j = 0; j < F_; ++j) {
            float s = mb2[j];
            for (int k = 0; k < F_; ++k) s += h1[k] * mw2[k * F_ + j];
            h2[j] = fmaxf(s, 0.0f);
        }
        for (int j = 0; j < F_; ++j) {
            float s = mb3[j];
            for (int k = 0; k < F_; ++k) s += h2[k] * mw3[k * F_ + j];
            float sc = fmaxf(s * 0.05f + sg, 0.0f) + 1e-9f;
            wsf[SINV_F + b * F_ + j] = 1.0f / sc;
            wsf[SLAM_F + b * F_ + j] = lamb_e * sc;
        }
    }
    if (tid == 50) {
        float lamb_e = expf(lamb[0]);
        float eps_e = expf(eps_om[0]);
        wsf[MISC_F + 0] = eps_e;
        wsf[MISC_F + 1] = 1.0f / (1.0f + lamb_e * (1.0f + eps_e));
    }
}

// ---------------- setup: fragment packing (grid-parallel) ----------------
__global__ void setup_pack(const float* __restrict__ Wf, float* __restrict__ wsf)
{
    unsigned short* wsu = (unsigned short*)wsf;
    const int gtid = blockIdx.x * TPB + threadIdx.x;
    for (int i = gtid; i < 49152; i += gridDim.x * TPB) {
        if (i < 24576) {
            // pass-1 A frags: M = row r (f*4+g), K = channel c; fold 1/scaling
            int j = i & 7, lane = (i >> 3) & 63;
            int t = i >> 9;                // 0..47
            int ks = t & 3, mt = t >> 2;
            int m = lane & 15, q = lane >> 4;
            int r = mt * 16 + m;
            int c = ks * 32 + q * 8 + j;
            int f = r >> 2, g = r & 3;
            float w = Wf[(g * F_ + f) * C_ + c];
#pragma unroll
            for (int b = 0; b < 2; ++b) {
                float v = w * wsf[SINV_F + b * F_ + f];
                unsigned short h = (unsigned short)(__float_as_uint(v) >> 16);
                float lo = v - bf2f(h);
                unsigned short l = (unsigned short)(__float_as_uint(lo) >> 16);
                wsu[P1_U + ((((b * 2 + 0) * 12 + mt) * 4 + ks) * 64 + lane) * 8 + j] = h;
                wsu[P1_U + ((((b * 2 + 1) * 12 + mt) * 4 + ks) * 64 + lane) * 8 + j] = l;
            }
        } else {
            // pass-2 A frags: M = channel, K = row; fold lamb_e*scaling
            int ii = i - 24576;
            int j = ii & 7, lane = (ii >> 3) & 63;
            int t = ii >> 9;
            int ks = t % 6, cmt = t / 6;
            int m = lane & 15, q = lane >> 4;
            int cch = cmt * 16 + m;
            int r = ks * 32 + q * 8 + j;
            int f = r >> 2, g = r & 3;
            float w = Wf[(g * F_ + f) * C_ + cch];
#pragma unroll
            for (int b = 0; b < 2; ++b) {
                float v = w * wsf[SLAM_F + b * F_ + f];
                unsigned short h = (unsigned short)(__float_as_uint(v) >> 16);
                float lo = v - bf2f(h);
                unsigned short l = (unsigned short)(__float_as_uint(lo) >> 16);
                wsu[P2_U + ((((b * 2 + 0) * 8 + cmt) * 6 + ks) * 64 + lane) * 8 + j] = h;
                wsu[P2_U + ((((b * 2 + 1) * 8 + cmt) * 6 + ks) * 64 + lane) * 8 + j] = l;
            }
        }
    }
}

// Euclidean projection of a 4-vector onto the unit l1 ball (per lane, in regs)
__device__ __forceinline__ void proj4(const float v[4], float o[4]) {
    float a0 = fabsf(v[0]), a1 = fabsf(v[1]), a2 = fabsf(v[2]), a3 = fabsf(v[3]);
    float sum = a0 + a1 + a2 + a3;
    float t0 = fmaxf(a0, a1), u0 = fminf(a0, a1);
    float t1 = fmaxf(a2, a3), u1 = fminf(a2, a3);
    float s0 = fmaxf(t0, t1), m0 = fminf(t0, t1);
    float m1 = fmaxf(u0, u1), s3 = fminf(u0, u1);
    float s1 = fmaxf(m1, m0), s2 = fminf(m1, m0);
    float c2 = s0 + s1, c3 = c2 + s2, c4 = c3 + s3;
    float th = s0 - 1.0f, rh = 1.0f;
    if (s1 * 2.0f > c2 - 1.0f) { th = c2 - 1.0f; rh = 2.0f; }
    if (s2 * 3.0f > c3 - 1.0f) { th = c3 - 1.0f; rh = 3.0f; }
    if (s3 * 4.0f > c4 - 1.0f) { th = c4 - 1.0f; rh = 4.0f; }
    float theta = fmaxf(th / rh, 0.0f);
    bool inside = (sum <= 1.0f);
#pragma unroll
    for (int g = 0; g < 4; ++g) {
        float ag = fabsf(v[g]);
        float pg = copysignf(fmaxf(ag - theta, 0.0f), v[g]);
        o[g] = inside ? v[g] : pg;
    }
}

// ---------------- main: 32-pixel tile per block, 1024 blocks ----------------
__global__ __launch_bounds__(TPB, 4) void mfoe_main(
    const float* __restrict__ xnoisy,
    const float* __restrict__ wsf,
    float* __restrict__ out,
    const int* __restrict__ n_iter_p)
{
    __shared__ __align__(16) unsigned short sXH[32 * XS];
    __shared__ __align__(16) unsigned short sXL[32 * XS];
    __shared__ __align__(16) unsigned short sACT[32 * AS];
    __shared__ __align__(16) float sQ[F_ * QS];

    const int tid = threadIdx.x;
    const int lane = tid & 63;
    const int wv = __builtin_amdgcn_readfirstlane(tid >> 6);   // SGPR wave id
    const int n = lane & 15;
    const int q = lane >> 4;
    const int blk = blockIdx.x;
    const int b = blk >> 9;                 // 512 blocks per image
    const int pix0 = (blk & 511) << 5;      // 32 pixels per block

    const float* __restrict__ xin = xnoisy + b * (C_ * HW) + pix0;
    float* __restrict__ oimg = out + b * (C_ * HW) + pix0;
    const unsigned short* __restrict__ wsu = (const unsigned short*)wsf;
    const int niter = *n_iter_p;

    if (niter == 0) {
        for (int i = tid; i < C_ * 32; i += TPB) {
            int p = i & 31, c = i >> 5;
            oimg[c * HW + p] = xin[c * HW + p];
        }
        return;
    }

    // stage x -> LDS bf16 hi/lo (truncation split: lo absorbs hi's error)
    for (int i = tid; i < C_ * 32; i += TPB) {
        int p = i & 31, c = i >> 5;
        float v = xin[c * HW + p];
        unsigned short h = (unsigned short)(__float_as_uint(v) >> 16);
        float lo = v - bf2f(h);
        sXH[p * XS + c] = h;
        sXL[p * XS + c] = (unsigned short)(__float_as_uint(lo) >> 16);
    }
    // stage activation params -> LDS (padded rows)
    for (int i = tid; i < F_ * 32; i += TPB)
        sQ[(i >> 5) * QS + (i & 31)] = wsf[QEQN_F + i];

    // preload this thread's x_noisy values (update layout)
    float xnr[16];
#pragma unroll
    for (int j = 0; j < 4; ++j) {
        int jw = wv * 4 + j, cmt = jw >> 1, nt = jw & 1;
        int p = nt * 16 + n;
#pragma unroll
        for (int reg = 0; reg < 4; ++reg)
            xnr[j * 4 + reg] = xin[(cmt * 16 + q * 4 + reg) * HW + p];
    }
    const float eps_e = wsf[MISC_F + 0];
    const float invden = wsf[MISC_F + 1];

    for (int it = 0; it < niter; ++it) {
        floatx4 acc2[4];
#pragma unroll
        for (int j = 0; j < 4; ++j) acc2[j] = (floatx4){0.f, 0.f, 0.f, 0.f};

#pragma unroll 1
        for (int h = 0; h < 2; ++h) {
            __syncthreads();   // x ready / act buffer free
            // ---- pass 1: 12 (mtile,ntile) jobs per half, 3 per wave
#pragma unroll 1
            for (int j = 0; j < 3; ++j) {
                int jw = wv * 3 + j, mtl = jw >> 1, nt = jw & 1;
                int mt = h * 6 + mtl;
                int p = nt * 16 + n;
                floatx4 acc = (floatx4){0.f, 0.f, 0.f, 0.f};
                const short8* aHp = (const short8*)(wsu + P1_U + (((b * 2 + 0) * 12 + mt) * 4) * 512 + lane * 8);
                const short8* aLp = (const short8*)(wsu + P1_U + (((b * 2 + 1) * 12 + mt) * 4) * 512 + lane * 8);
#pragma unroll
                for (int ks = 0; ks < 4; ++ks) {
                    short8 aH = aHp[ks * 64];
                    short8 aL = aLp[ks * 64];
                    short8 bH = *(const short8*)&sXH[p * XS + ks * 32 + q * 8];
                    short8 bL = *(const short8*)&sXL[p * XS + ks * 32 + q * 8];
                    acc = __builtin_amdgcn_mfma_f32_16x16x32_bf16(aH, bH, acc, 0, 0, 0);
                    acc = __builtin_amdgcn_mfma_f32_16x16x32_bf16(aH, bL, acc, 0, 0, 0);
                    acc = __builtin_amdgcn_mfma_f32_16x16x32_bf16(aL, bH, acc, 0, 0, 0);
                }
                // ---- activation in D-regs: lane owns (f, pixel p)
                int f = h * 24 + mtl * 4 + q;
                float qv[32];
#pragma unroll
                for (int k = 0; k < 8; ++k)
                    *(floatx4*)&qv[4 * k] = *(const floatx4*)&sQ[f * QS + 4 * k];
                float v[4] = {acc[0], acc[1], acc[2], acc[3]};
                float pv[4]; proj4(v, pv);
                float y[4];
#pragma unroll
                for (int l = 0; l < 4; ++l)
                    y[l] = fmaf(qv[l * 4 + 0], v[0], fmaf(qv[l * 4 + 1], v[1],
                           fmaf(qv[l * 4 + 2], v[2], qv[l * 4 + 3] * v[3])));
                float py[4]; proj4(y, py);
                float m2[4];
#pragma unroll
                for (int g = 0; g < 4; ++g) m2[g] = fmaf(eps_e, y[g], py[g]);
                unsigned pk0, pk1;
                {
                    float a0, a1;
                    float gcc0 = fmaf(qv[16 + 0], m2[0], fmaf(qv[16 + 4], m2[1],
                                 fmaf(qv[16 + 8], m2[2], qv[16 + 12] * m2[3])));
                    a0 = fmaf(eps_e, v[0], pv[0]) - gcc0;
                    float gcc1 = fmaf(qv[17 + 0], m2[0], fmaf(qv[17 + 4], m2[1],
                                 fmaf(qv[17 + 8], m2[2], qv[17 + 12] * m2[3])));
                    a1 = fmaf(eps_e, v[1], pv[1]) - gcc1;
                    pk0 = ((unsigned)f2bf(a1) << 16) | f2bf(a0);
                    float gcc2 = fmaf(qv[18 + 0], m2[0], fmaf(qv[18 + 4], m2[1],
                                 fmaf(qv[18 + 8], m2[2], qv[18 + 12] * m2[3])));
                    a0 = fmaf(eps_e, v[2], pv[2]) - gcc2;
                    float gcc3 = fmaf(qv[19 + 0], m2[0], fmaf(qv[19 + 4], m2[1],
                                 fmaf(qv[19 + 8], m2[2], qv[19 + 12] * m2[3])));
                    a1 = fmaf(eps_e, v[3], pv[3]) - gcc3;
                    pk1 = ((unsigned)f2bf(a1) << 16) | f2bf(a0);
                }
                unsigned long long pk = ((unsigned long long)pk1 << 32) | pk0;
                *(unsigned long long*)&sACT[p * AS + mtl * 16 + q * 4] = pk;
            }
            __syncthreads();   // act ready
            // ---- pass 2 partial: 16 (ctile,ntile) jobs, 4 per wave
#pragma unroll
            for (int j = 0; j < 4; ++j) {
                int jw = wv * 4 + j, cmt = jw >> 1, nt = jw & 1;
                int p = nt * 16 + n;
                const short8* a2H = (const short8*)(wsu + P2_U + (((b * 2 + 0) * 8 + cmt) * 6 + h * 3) * 512 + lane * 8);
                const short8* a2L = (const short8*)(wsu + P2_U + (((b * 2 + 1) * 8 + cmt) * 6 + h * 3) * 512 + lane * 8);
                floatx4 a = acc2[j];
#pragma unroll
                for (int ksl = 0; ksl < 3; ++ksl) {
                    short8 aH = a2H[ksl * 64];
                    short8 aL = a2L[ksl * 64];
                    short8 bA = *(const short8*)&sACT[p * AS + ksl * 32 + q * 8];
                    a = __builtin_amdgcn_mfma_f32_16x16x32_bf16(aH, bA, a, 0, 0, 0);
                    a = __builtin_amdgcn_mfma_f32_16x16x32_bf16(aL, bA, a, 0, 0, 0);
                }
                acc2[j] = a;
            }
        }
        // ---- update: thread owns (cmt,q,nt) cells; trunc hi/lo repack
        const bool last = (it == niter - 1);
#pragma unroll
        for (int j = 0; j < 4; ++j) {
            int jw = wv * 4 + j, cmt = jw >> 1, nt = jw & 1;
            int p = nt * 16 + n;
            int cb = cmt * 16 + q * 4;
            unsigned long long oh = *(const unsigned long long*)&sXH[p * XS + cb];
            unsigned long long ol = *(const unsigned long long*)&sXL[p * XS + cb];
            unsigned long long nh = 0ull, nl = 0ull;
#pragma unroll
            for (int reg = 0; reg < 4; ++reg) {
                float xo = bf2f((unsigned short)(oh >> (16 * reg))) +
                           bf2f((unsigned short)(ol >> (16 * reg)));
                float nx = xo - (xo - xnr[j * 4 + reg] + acc2[j][reg]) * invden;
                if (last) oimg[(cb + reg) * HW + p] = nx;
                unsigned short hh = (unsigned short)(__float_as_uint(nx) >> 16);
                float lo = nx - bf2f(hh);
                unsigned short ll = (unsigned short)(__float_as_uint(lo) >> 16);
                nh |= ((unsigned long long)hh) << (16 * reg);
                nl |= ((unsigned long long)ll) << (16 * reg);
            }
            *(unsigned long long*)&sXH[p * XS + cb] = nh;
            *(unsigned long long*)&sXL[p * XS + cb] = nl;
        }
    }
}

extern "C" void kernel_launch(void* const* d_in, const int* in_sizes, int n_in,
                              void* d_out, int out_size, void* d_ws, size_t ws_size,
                              hipStream_t stream) {
    const float* x_noisy = (const float*)d_in[0];
    const float* sigma   = (const float*)d_in[1];
    const float* Qp      = (const float*)d_in[2];
    const float* taus_p  = (const float*)d_in[3];
    const float* lamb    = (const float*)d_in[4];
    const float* eps_om  = (const float*)d_in[5];
    const float* mw1     = (const float*)d_in[6];
    const float* mb1     = (const float*)d_in[7];
    const float* mw2     = (const float*)d_in[8];
    const float* mb2     = (const float*)d_in[9];
    const float* mw3     = (const float*)d_in[10];
    const float* mb3     = (const float*)d_in[11];
    const float* Wf      = (const float*)d_in[12];
    const int*   n_iter  = (const int*)d_in[13];
    float* out = (float*)d_out;
    float* ws  = (float*)d_ws;

    hipLaunchKernelGGL(setup_math, dim3(1), dim3(64), 0, stream,
                       sigma, Qp, taus_p, lamb, eps_om,
                       mw1, mb1, mw2, mb2, mw3, mb3, ws);
    hipLaunchKernelGGL(setup_pack, dim3(192), dim3(TPB), 0, stream, Wf, ws);
    hipLaunchKernelGGL(mfoe_main, dim3(1024), dim3(TPB), 0, stream,
                       x_noisy, ws, out, n_iter);
}